// Round 7
// baseline (2971.522 us; speedup 1.0000x reference)
//
#include <hip/hip_runtime.h>
#include <hip/hip_bf16.h>

typedef __bf16  bf16x8  __attribute__((ext_vector_type(8)));
typedef short   short8_t __attribute__((ext_vector_type(8)));
typedef float   float4_t __attribute__((ext_vector_type(4)));

#define MFMA(a, b, c) __builtin_amdgcn_mfma_f32_16x16x32_bf16((a), (b), (c), 0, 0, 0)

#define LOG2E      1.4426950408889634f
#define TWO_LOG2E  2.8853900817779268f

__device__ __forceinline__ unsigned short f2bf(float f) {
  unsigned u = __builtin_bit_cast(unsigned, f);
  unsigned r = ((u >> 16) & 1u) + 0x7FFFu;   // round-to-nearest-even
  return (unsigned short)((u + r) >> 16);
}
// x pre-scaled by LOG2E
__device__ __forceinline__ float sig2(float x) {
  return __builtin_amdgcn_rcpf(1.f + __builtin_amdgcn_exp2f(-x));
}
// x pre-scaled by 2*LOG2E
__device__ __forceinline__ float tanh2s(float x) {
  return 1.f - 2.f * __builtin_amdgcn_rcpf(1.f + __builtin_amdgcn_exp2f(x));
}

// 256 blocks x 512 threads (8 waves), 32 rows/block. Wave w owns hidden units
// [16w,16w+16). R4 schedule with h1 double-buffered (static addresses via
// 2x-unrolled loop). Step t: RB holds h1(t-1), WB holds dead h1(t-2); proj
// writes xf(t) into WB's first 2 KiB (dead corner), act1 writes h1(t) over
// the whole WB. 3 __syncthreads per step:
//   R1': cell0 h-part MFMA (32, reads h0f(t-1))
//        + proj (w<4, t>0: reads RB -> x(t); writes xf -> WB corner)
//   b1   (WAR h0f(t-1); xf publish)
//   R2': x-part MFMA (8, reads WB corner) + act0 m-interleaved -> h0f(t)
//   b2   (h0f(t) publish)
//   R3': x(t) stores (drain at b3 behind 64 MFMA) + cell1 MFMA (reads h0f(t),
//        RB) + act1 m-interleaved -> writes WB = h1(t) directly (no WAR)
//   b3   (h1(t) publish; RB reads done)
__global__ __launch_bounds__(512, 2) void lstm_roll(
    const float* __restrict__ x0,  const float* __restrict__ W0,
    const float* __restrict__ b0v, const float* __restrict__ W1,
    const float* __restrict__ b1v, const float* __restrict__ Wout,
    const float* __restrict__ bout, const float* __restrict__ dts,
    const int* __restrict__ nsp,   float* __restrict__ out)
{
  __shared__ __align__(16) unsigned short w0h[8 * 4 * 4 * 512];  // 128 KiB W0 h-part B-frags [w][g][kt]
  __shared__ __align__(16) unsigned short woutF[2 * 4 * 512];    //   8 KiB Wout B-frags (dts*DT folded)
  __shared__ __align__(16) unsigned short h0f[4 * 2 * 512];      //   8 KiB h0 A-frags [kt][m]
  __shared__ __align__(16) unsigned short h1fA[4 * 2 * 512];     //   8 KiB h1 A-frags, buffer A
  __shared__ __align__(16) unsigned short h1fB[4 * 2 * 512];     //   8 KiB h1 A-frags, buffer B

  const int tid = threadIdx.x;
  const int w   = tid >> 6;
  const int l   = tid & 63;
  const int lm  = l & 15;
  const int lh  = l >> 4;
  const int T   = nsp[0];                 // 512 (even; loop 2x-unrolled)
  const long rowStride = (long)(T + 1) * 32;
  const long bbase = (long)blockIdx.x * 32;

  // ---------------- weight gather / packing (once) ----------------
  bf16x8 w0x[4];       // W0 x-part B-frags (K=32)
  bf16x8 w1f[4][8];    // W1 B-frags (K=256; kt 0..3 h0-part, 4..7 h1-part)
  #pragma unroll
  for (int g = 0; g < 4; ++g) {
    const float sc = (g == 2) ? TWO_LOG2E : LOG2E;
    const int col = g * 128 + w * 16 + lm;
    {
      short8_t t8;
      #pragma unroll
      for (int e = 0; e < 8; ++e) t8[e] = (short)f2bf(sc * W0[(lh * 8 + e) * 512 + col]);
      w0x[g] = __builtin_bit_cast(bf16x8, t8);
    }
    #pragma unroll
    for (int kt = 0; kt < 8; ++kt) {
      short8_t t8;
      #pragma unroll
      for (int e = 0; e < 8; ++e) t8[e] = (short)f2bf(sc * W1[(kt * 32 + lh * 8 + e) * 512 + col]);
      w1f[g][kt] = __builtin_bit_cast(bf16x8, t8);
    }
    #pragma unroll
    for (int kt = 0; kt < 4; ++kt) {
      const int base = (((w * 4 + g) * 4) + kt) * 512 + l * 8;
      #pragma unroll
      for (int e = 0; e < 8; ++e)
        w0h[base + e] = f2bf(sc * W0[(32 + kt * 32 + lh * 8 + e) * 512 + col]);
    }
  }
  { // Wout B-frags with dts*DT folded in; 8 frags, one per wave
    const int n = w & 1, kt = w >> 1;
    if (kt < 4) {
      const float csc = dts[n * 16 + lm] * 0.01f;
      const int base = (n * 4 + kt) * 512 + l * 8;
      #pragma unroll
      for (int e = 0; e < 8; ++e)
        woutF[base + e] = f2bf(csc * Wout[(kt * 32 + lh * 8 + e) * 32 + (n * 16 + lm)]);
    }
  }
  float b0r[4], b1r[4];
  #pragma unroll
  for (int g = 0; g < 4; ++g) {
    const float sc = (g == 2) ? TWO_LOG2E : LOG2E;
    b0r[g] = sc * b0v[g * 128 + w * 16 + lm];
    b1r[g] = sc * b1v[g * 128 + w * 16 + lm];
  }

  // proj mapping: waves 0..3 own (m_c, n_c) output quadrant
  const int m_c = w & 1, n_c = (w >> 1) & 1;
  float boutr = 0.f, xr[4] = {0.f, 0.f, 0.f, 0.f};
  long obase0 = 0;
  int  xfbase = 0;
  if (w < 4) {
    boutr = bout[n_c * 16 + lm] * dts[n_c * 16 + lm] * 0.01f;
    const int kin = n_c * 16 + lm;
    xfbase = m_c * 512 + (lh * 4 + 16 * (kin >> 3)) * 8 + (kin & 7);
    obase0 = (bbase + m_c * 16 + lh * 4) * rowStride + (n_c * 16 + lm);
    #pragma unroll
    for (int r = 0; r < 4; ++r) {
      xr[r] = x0[(bbase + m_c * 16 + lh * 4 + r) * 32 + n_c * 16 + lm];
      out[obase0 + r * rowStride] = xr[r];   // trajectory t = 0
      h1fB[xfbase + r * 8] = f2bf(xr[r]);    // xf(0) in step-0 WB corner
    }
  }
  for (int i = tid; i < 4 * 2 * 512; i += 512) { h0f[i] = 0; h1fA[i] = 0; }

  // h-write scatter base (fragment layout; same for h0f/h1f)
  const int hwb = ((w >> 1) * 2) * 512 +
                  (lh * 4 + 16 * (2 * (w & 1) + ((lm >> 3) & 1))) * 8 + (lm & 7);

  float4_t c0[2], c1[2];
  #pragma unroll
  for (int m = 0; m < 2; ++m) {
    c0[m] = (float4_t){0.f, 0.f, 0.f, 0.f};
    c1[m] = (float4_t){0.f, 0.f, 0.f, 0.f};
  }

#define STEP(T_IDX, RB, WB) do {                                               \
    /* ---- R1': cell0 h-part + proj(h1(t-1)) ---- */                          \
    float4_t acc0[2][4];                                                       \
    _Pragma("unroll")                                                          \
    for (int g = 0; g < 4; ++g) {                                              \
      acc0[0][g] = (float4_t){b0r[g], b0r[g], b0r[g], b0r[g]};                 \
      acc0[1][g] = (float4_t){b0r[g], b0r[g], b0r[g], b0r[g]};                 \
    }                                                                          \
    _Pragma("unroll")                                                          \
    for (int kt = 0; kt < 4; ++kt) {                                           \
      const bf16x8 a0 = *(const bf16x8*)&h0f[(kt * 2 + 0) * 512 + l * 8];      \
      const bf16x8 a1 = *(const bf16x8*)&h0f[(kt * 2 + 1) * 512 + l * 8];      \
      _Pragma("unroll")                                                        \
      for (int g = 0; g < 4; ++g) {                                            \
        const bf16x8 bw = *(const bf16x8*)&w0h[(((w * 4 + g) * 4) + kt) * 512 + l * 8]; \
        acc0[0][g] = MFMA(a0, bw, acc0[0][g]);                                 \
        acc0[1][g] = MFMA(a1, bw, acc0[1][g]);                                 \
      }                                                                        \
    }                                                                          \
    if (w < 4 && (T_IDX) > 0) {                                                \
      float4_t dacc = (float4_t){boutr, boutr, boutr, boutr};                  \
      _Pragma("unroll")                                                        \
      for (int kt = 0; kt < 4; ++kt) {                                         \
        const bf16x8 a  = *(const bf16x8*)&(RB)[(kt * 2 + m_c) * 512 + l * 8]; \
        const bf16x8 bw = *(const bf16x8*)&woutF[(n_c * 4 + kt) * 512 + l * 8]; \
        dacc = MFMA(a, bw, dacc);                                              \
      }                                                                        \
      _Pragma("unroll")                                                        \
      for (int r = 0; r < 4; ++r) {                                            \
        xr[r] += dacc[r];                                                      \
        (WB)[xfbase + r * 8] = f2bf(xr[r]);                                    \
      }                                                                        \
    }                                                                          \
    __syncthreads();   /* b1 */                                                \
    /* ---- R2': x-part + act0 (m-interleaved) -> h0f(t) ---- */               \
    {                                                                          \
      const bf16x8 ax0 = *(const bf16x8*)&(WB)[l * 8];                         \
      _Pragma("unroll")                                                        \
      for (int g = 0; g < 4; ++g) acc0[0][g] = MFMA(ax0, w0x[g], acc0[0][g]);  \
      const bf16x8 ax1 = *(const bf16x8*)&(WB)[512 + l * 8];                   \
      _Pragma("unroll")                                                        \
      for (int r = 0; r < 4; ++r) {                                            \
        const float iv = sig2(acc0[0][0][r]);                                  \
        const float fv = sig2(acc0[0][1][r]);                                  \
        const float gv = tanh2s(acc0[0][2][r]);                                \
        const float ov = sig2(acc0[0][3][r]);                                  \
        const float cc = fv * c0[0][r] + iv * gv;                              \
        c0[0][r] = cc;                                                         \
        h0f[hwb + r * 8] = f2bf(ov * tanh2s(cc * TWO_LOG2E));                  \
      }                                                                        \
      _Pragma("unroll")                                                        \
      for (int g = 0; g < 4; ++g) acc0[1][g] = MFMA(ax1, w0x[g], acc0[1][g]);  \
      _Pragma("unroll")                                                        \
      for (int r = 0; r < 4; ++r) {                                            \
        const float iv = sig2(acc0[1][0][r]);                                  \
        const float fv = sig2(acc0[1][1][r]);                                  \
        const float gv = tanh2s(acc0[1][2][r]);                                \
        const float ov = sig2(acc0[1][3][r]);                                  \
        const float cc = fv * c0[1][r] + iv * gv;                              \
        c0[1][r] = cc;                                                         \
        h0f[hwb + 512 + r * 8] = f2bf(ov * tanh2s(cc * TWO_LOG2E));            \
      }                                                                        \
    }                                                                          \
    __syncthreads();   /* b2 */                                                \
    /* ---- R3': stores + cell1 + act1 -> WB = h1(t) ---- */                   \
    if (w < 4 && (T_IDX) > 0) {                                                \
      const long ob = obase0 + (long)(T_IDX) * 32;                             \
      _Pragma("unroll")                                                        \
      for (int r = 0; r < 4; ++r) out[ob + r * rowStride] = xr[r];             \
    }                                                                          \
    float4_t acc1[2][4];                                                       \
    _Pragma("unroll")                                                          \
    for (int g = 0; g < 4; ++g) {                                              \
      acc1[0][g] = (float4_t){b1r[g], b1r[g], b1r[g], b1r[g]};                 \
      acc1[1][g] = (float4_t){b1r[g], b1r[g], b1r[g], b1r[g]};                 \
    }                                                                          \
    _Pragma("unroll")                                                          \
    for (int kt = 0; kt < 4; ++kt) {                                           \
      const bf16x8 a = *(const bf16x8*)&h0f[(kt * 2 + 0) * 512 + l * 8];       \
      _Pragma("unroll")                                                        \
      for (int g = 0; g < 4; ++g) acc1[0][g] = MFMA(a, w1f[g][kt], acc1[0][g]); \
    }                                                                          \
    _Pragma("unroll")                                                          \
    for (int kt = 0; kt < 4; ++kt) {                                           \
      const bf16x8 a = *(const bf16x8*)&(RB)[(kt * 2 + 0) * 512 + l * 8];      \
      _Pragma("unroll")                                                        \
      for (int g = 0; g < 4; ++g) acc1[0][g] = MFMA(a, w1f[g][kt + 4], acc1[0][g]); \
    }                                                                          \
    _Pragma("unroll")                                                          \
    for (int r = 0; r < 4; ++r) {                                              \
      const float iv = sig2(acc1[0][0][r]);                                    \
      const float fv = sig2(acc1[0][1][r]);                                    \
      const float gv = tanh2s(acc1[0][2][r]);                                  \
      const float ov = sig2(acc1[0][3][r]);                                    \
      const float cc = fv * c1[0][r] + iv * gv;                                \
      c1[0][r] = cc;                                                           \
      (WB)[hwb + r * 8] = f2bf(ov * tanh2s(cc * TWO_LOG2E));                   \
    }                                                                          \
    _Pragma("unroll")                                                          \
    for (int kt = 0; kt < 4; ++kt) {                                           \
      const bf16x8 a = *(const bf16x8*)&h0f[(kt * 2 + 1) * 512 + l * 8];       \
      _Pragma("unroll")                                                        \
      for (int g = 0; g < 4; ++g) acc1[1][g] = MFMA(a, w1f[g][kt], acc1[1][g]); \
    }                                                                          \
    _Pragma("unroll")                                                          \
    for (int kt = 0; kt < 4; ++kt) {                                           \
      const bf16x8 a = *(const bf16x8*)&(RB)[(kt * 2 + 1) * 512 + l * 8];      \
      _Pragma("unroll")                                                        \
      for (int g = 0; g < 4; ++g) acc1[1][g] = MFMA(a, w1f[g][kt + 4], acc1[1][g]); \
    }                                                                          \
    _Pragma("unroll")                                                          \
    for (int r = 0; r < 4; ++r) {                                              \
      const float iv = sig2(acc1[1][0][r]);                                    \
      const float fv = sig2(acc1[1][1][r]);                                    \
      const float gv = tanh2s(acc1[1][2][r]);                                  \
      const float ov = sig2(acc1[1][3][r]);                                    \
      const float cc = fv * c1[1][r] + iv * gv;                                \
      c1[1][r] = cc;                                                           \
      (WB)[hwb + 512 + r * 8] = f2bf(ov * tanh2s(cc * TWO_LOG2E));             \
    }                                                                          \
    __syncthreads();   /* b3 */                                                \
  } while (0)

  __syncthreads();   // publish packing, xf(0), h0f/h1fA zeros

  #pragma unroll 1
  for (int t = 0; t < T; t += 2) {
    STEP(t,     h1fA, h1fB);
    STEP(t + 1, h1fB, h1fA);
  }

  // ============ Epilogue: x(T) from h1(T-1) (in h1fA since T even) ============
  if (w < 4) {
    float4_t dacc = (float4_t){boutr, boutr, boutr, boutr};
    #pragma unroll
    for (int kt = 0; kt < 4; ++kt) {
      const bf16x8 a  = *(const bf16x8*)&h1fA[(kt * 2 + m_c) * 512 + l * 8];
      const bf16x8 bw = *(const bf16x8*)&woutF[(n_c * 4 + kt) * 512 + l * 8];
      dacc = MFMA(a, bw, dacc);
    }
    const long ob = obase0 + (long)T * 32;
    #pragma unroll
    for (int r = 0; r < 4; ++r) {
      xr[r] += dacc[r];
      out[ob + r * rowStride] = xr[r];
    }
  }
}

extern "C" void kernel_launch(void* const* d_in, const int* in_sizes, int n_in,
                              void* d_out, int out_size, void* d_ws, size_t ws_size,
                              hipStream_t stream) {
  (void)n_in; (void)out_size; (void)d_ws; (void)ws_size;
  const float* x0   = (const float*)d_in[0];
  const float* W0   = (const float*)d_in[1];
  const float* b0   = (const float*)d_in[2];
  const float* W1   = (const float*)d_in[3];
  const float* b1   = (const float*)d_in[4];
  const float* Wout = (const float*)d_in[5];
  const float* bout = (const float*)d_in[6];
  const float* dts  = (const float*)d_in[7];
  const int*   nsp  = (const int*)d_in[8];
  float* out = (float*)d_out;

  const int B    = in_sizes[0] / 32;   // 8192
  const int grid = B / 32;             // 256 blocks, 32 batch rows each
  lstm_roll<<<dim3(grid), dim3(512), 0, stream>>>(x0, W0, b0, W1, b1, Wout, bout, dts, nsp, out);
}

// Round 8
// 2311.119 us; speedup vs baseline: 1.2857x; 1.2857x over previous
//
#include <hip/hip_runtime.h>
#include <hip/hip_bf16.h>

typedef __bf16  bf16x8  __attribute__((ext_vector_type(8)));
typedef short   short8_t __attribute__((ext_vector_type(8)));
typedef float   float4_t __attribute__((ext_vector_type(4)));

#define MFMA(a, b, c) __builtin_amdgcn_mfma_f32_16x16x32_bf16((a), (b), (c), 0, 0, 0)

#define LOG2E      1.4426950408889634f
#define TWO_LOG2E  2.8853900817779268f

__device__ __forceinline__ unsigned short f2bf(float f) {
  unsigned u = __builtin_bit_cast(unsigned, f);
  unsigned r = ((u >> 16) & 1u) + 0x7FFFu;   // round-to-nearest-even
  return (unsigned short)((u + r) >> 16);
}
// x pre-scaled by LOG2E
__device__ __forceinline__ float sig2(float x) {
  return __builtin_amdgcn_rcpf(1.f + __builtin_amdgcn_exp2f(-x));
}
// x pre-scaled by 2*LOG2E
__device__ __forceinline__ float tanh2s(float x) {
  return 1.f - 2.f * __builtin_amdgcn_rcpf(1.f + __builtin_amdgcn_exp2f(x));
}

// 256 blocks x 512 threads (8 waves), 32 rows/block, TWO 16-row streams
// (s0 = rows 0-15, s1 = rows 16-31) phase-shifted one region apart so each
// barrier region co-schedules an MFMA-heavy phase of one stream with the
// VALU/trans-heavy phase of the other. Wave w owns hidden units [16w,16w+16).
// Per step, 4 __syncthreads:
//   R1: cell0h(s0,t) [16 MFMA] + proj(s0,t) [w<2] ; h1f1 <- h1n1(t-1)
//   R2: x-part+act0(s0) -> h0f0(t) ; cell0h(s1,t) + proj(s1,t) [w=2,3]
//   R3: stores x0(t) ; cell1(s0) -> h1n0 regs ; x-part+act0(s1) -> h0f1(t)
//   R4: stores x1(t) ; h1f0 <- h1n0 ; cell1(s1) -> h1n1 regs
// All stream buffers are distinct named arrays -> fully static LDS addresses,
// no loop unrolling. Single-buffered h state per stream (writes deferred one
// region past last reader, barrier between).
__global__ __launch_bounds__(512, 2) void lstm_roll(
    const float* __restrict__ x0,  const float* __restrict__ W0,
    const float* __restrict__ b0v, const float* __restrict__ W1,
    const float* __restrict__ b1v, const float* __restrict__ Wout,
    const float* __restrict__ bout, const float* __restrict__ dts,
    const int* __restrict__ nsp,   float* __restrict__ out)
{
  __shared__ __align__(16) unsigned short w0h[8 * 4 * 4 * 512];  // 128 KiB W0 h-part B-frags [w][g][kt]
  __shared__ __align__(16) unsigned short woutF[2 * 4 * 512];    //   8 KiB Wout B-frags (dts*DT folded)
  __shared__ __align__(16) unsigned short h0f0[4 * 512];         //   4 KiB h0 A-frags, stream0
  __shared__ __align__(16) unsigned short h0f1[4 * 512];         //   4 KiB h0 A-frags, stream1
  __shared__ __align__(16) unsigned short h1f0[4 * 512];         //   4 KiB h1 A-frags, stream0
  __shared__ __align__(16) unsigned short h1f1[4 * 512];         //   4 KiB h1 A-frags, stream1
  __shared__ __align__(16) unsigned short xf0[512];              //   1 KiB x A-frag, stream0
  __shared__ __align__(16) unsigned short xf1[512];              //   1 KiB x A-frag, stream1

  const int tid = threadIdx.x;
  const int w   = tid >> 6;
  const int l   = tid & 63;
  const int lm  = l & 15;
  const int lh  = l >> 4;
  const int T   = nsp[0];
  const long rowStride = (long)(T + 1) * 32;
  const long bbase = (long)blockIdx.x * 32;

  // ---------------- weight gather / packing (once, same as R4) ----------------
  bf16x8 w0x[4];       // W0 x-part B-frags (K=32)
  bf16x8 w1f[4][8];    // W1 B-frags (K=256; kt 0..3 h0-part, 4..7 h1-part)
  #pragma unroll
  for (int g = 0; g < 4; ++g) {
    const float sc = (g == 2) ? TWO_LOG2E : LOG2E;
    const int col = g * 128 + w * 16 + lm;
    {
      short8_t t8;
      #pragma unroll
      for (int e = 0; e < 8; ++e) t8[e] = (short)f2bf(sc * W0[(lh * 8 + e) * 512 + col]);
      w0x[g] = __builtin_bit_cast(bf16x8, t8);
    }
    #pragma unroll
    for (int kt = 0; kt < 8; ++kt) {
      short8_t t8;
      #pragma unroll
      for (int e = 0; e < 8; ++e) t8[e] = (short)f2bf(sc * W1[(kt * 32 + lh * 8 + e) * 512 + col]);
      w1f[g][kt] = __builtin_bit_cast(bf16x8, t8);
    }
    #pragma unroll
    for (int kt = 0; kt < 4; ++kt) {
      const int base = (((w * 4 + g) * 4) + kt) * 512 + l * 8;
      #pragma unroll
      for (int e = 0; e < 8; ++e)
        w0h[base + e] = f2bf(sc * W0[(32 + kt * 32 + lh * 8 + e) * 512 + col]);
    }
  }
  { // Wout B-frags with dts*DT folded in
    const int n = w & 1, kt = w >> 1;
    if (kt < 4) {
      const float csc = dts[n * 16 + lm] * 0.01f;
      const int base = (n * 4 + kt) * 512 + l * 8;
      #pragma unroll
      for (int e = 0; e < 8; ++e)
        woutF[base + e] = f2bf(csc * Wout[(kt * 32 + lh * 8 + e) * 32 + (n * 16 + lm)]);
    }
  }
  float b0r[4], b1r[4];
  #pragma unroll
  for (int g = 0; g < 4; ++g) {
    const float sc = (g == 2) ? TWO_LOG2E : LOG2E;
    b0r[g] = sc * b0v[g * 128 + w * 16 + lm];
    b1r[g] = sc * b1v[g * 128 + w * 16 + lm];
  }

  // proj/store mapping: waves 0,1 -> stream0 (n_c = w&1); waves 2,3 -> stream1
  const int S_w = (w >> 1) & 1;
  const int n_c = w & 1;
  float boutr = 0.f, xr[4] = {0.f, 0.f, 0.f, 0.f};
  long obase0 = 0;
  int  xfb = 0;
  if (w < 4) {
    boutr = bout[n_c * 16 + lm] * dts[n_c * 16 + lm] * 0.01f;
    const int kin = n_c * 16 + lm;
    xfb = (lh * 4 + 16 * (kin >> 3)) * 8 + (kin & 7);
    obase0 = (bbase + S_w * 16 + lh * 4) * rowStride + (n_c * 16 + lm);
    unsigned short* xfS = S_w ? xf1 : xf0;
    #pragma unroll
    for (int r = 0; r < 4; ++r) {
      xr[r] = x0[(bbase + S_w * 16 + lh * 4 + r) * 32 + n_c * 16 + lm];
      out[obase0 + r * rowStride] = xr[r];   // trajectory t = 0
      xfS[xfb + r * 8] = f2bf(xr[r]);        // seed xf(0)
    }
  }
  for (int i = tid; i < 4 * 512; i += 512) {
    h0f0[i] = 0; h0f1[i] = 0; h1f0[i] = 0; h1f1[i] = 0;
  }

  // h-write scatter base (per-stream fragment layout; kt = w>>1)
  const int hwb = (w >> 1) * 512 +
                  (lh * 4 + 16 * (2 * (w & 1) + ((lm >> 3) & 1))) * 8 + (lm & 7);

  float4_t c0s0 = {0.f,0.f,0.f,0.f}, c0s1 = {0.f,0.f,0.f,0.f};
  float4_t c1s0 = {0.f,0.f,0.f,0.f}, c1s1 = {0.f,0.f,0.f,0.f};
  float h1n1[4] = {0.f,0.f,0.f,0.f};   // s1's h1(t) pending write (crosses iters)

#define INIT4(ACC, B) \
    _Pragma("unroll") \
    for (int g = 0; g < 4; ++g) (ACC)[g] = (float4_t){(B)[g], (B)[g], (B)[g], (B)[g]};

#define CELL0H(HSRC, ACC) \
    _Pragma("unroll") \
    for (int kt = 0; kt < 4; ++kt) { \
      const bf16x8 a = *(const bf16x8*)&(HSRC)[kt * 512 + l * 8]; \
      _Pragma("unroll") \
      for (int g = 0; g < 4; ++g) { \
        const bf16x8 bw = *(const bf16x8*)&w0h[(((w * 4 + g) * 4) + kt) * 512 + l * 8]; \
        (ACC)[g] = MFMA(a, bw, (ACC)[g]); \
      } \
    }

#define XPART(XSRC, ACC) { \
    const bf16x8 ax = *(const bf16x8*)&(XSRC)[l * 8]; \
    _Pragma("unroll") \
    for (int g = 0; g < 4; ++g) (ACC)[g] = MFMA(ax, w0x[g], (ACC)[g]); \
  }

#define CELL1A(H0SRC, AM) \
    _Pragma("unroll") \
    for (int kt = 0; kt < 4; ++kt) { \
      const bf16x8 a = *(const bf16x8*)&(H0SRC)[kt * 512 + l * 8]; \
      _Pragma("unroll") \
      for (int g = 0; g < 4; ++g) (AM)[g] = MFMA(a, w1f[g][kt], (AM)[g]); \
    }
#define CELL1B(H1SRC, AM) \
    _Pragma("unroll") \
    for (int kt = 0; kt < 4; ++kt) { \
      const bf16x8 a = *(const bf16x8*)&(H1SRC)[kt * 512 + l * 8]; \
      _Pragma("unroll") \
      for (int g = 0; g < 4; ++g) (AM)[g] = MFMA(a, w1f[g][kt + 4], (AM)[g]); \
    }

// LSTM elementwise: ACC (float4_t[4] gates), CS (float4_t cell state), then
// per-r DST receives hv (the new h value).
#define ACT4(ACC, CS, DST) \
    _Pragma("unroll") \
    for (int r = 0; r < 4; ++r) { \
      const float iv = sig2((ACC)[0][r]); \
      const float fv = sig2((ACC)[1][r]); \
      const float gv = tanh2s((ACC)[2][r]); \
      const float ov = sig2((ACC)[3][r]); \
      const float cc = fv * (CS)[r] + iv * gv; \
      (CS)[r] = cc; \
      const float hv = ov * tanh2s(cc * TWO_LOG2E); \
      DST; \
    }

#define PROJ(H1SRC, XFDST) { \
    float4_t dacc = (float4_t){boutr, boutr, boutr, boutr}; \
    _Pragma("unroll") \
    for (int kt = 0; kt < 4; ++kt) { \
      const bf16x8 a  = *(const bf16x8*)&(H1SRC)[kt * 512 + l * 8]; \
      const bf16x8 bw = *(const bf16x8*)&woutF[(n_c * 4 + kt) * 512 + l * 8]; \
      dacc = MFMA(a, bw, dacc); \
    } \
    _Pragma("unroll") \
    for (int r = 0; r < 4; ++r) { \
      xr[r] += dacc[r]; \
      (XFDST)[xfb + r * 8] = f2bf(xr[r]); \
    } \
  }

  __syncthreads();   // publish packing, xf seeds, h zeros

  #pragma unroll 1
  for (int t = 0; t < T; ++t) {
    // ===== R1: cell0h(s0) + proj(s0) ; h1f1 <- h1n1(t-1) =====
    float4_t acc0s0[4];
    INIT4(acc0s0, b0r);
    CELL0H(h0f0, acc0s0);
    if (t > 0) {
      #pragma unroll
      for (int r = 0; r < 4; ++r) h1f1[hwb + r * 8] = f2bf(h1n1[r]);
      if (w < 2) PROJ(h1f0, xf0);
    }
    __syncthreads();

    // ===== R2: x-part+act0(s0) -> h0f0 ; cell0h(s1) + proj(s1) =====
    float4_t acc0s1[4];
    XPART(xf0, acc0s0);
    INIT4(acc0s1, b0r);
    CELL0H(h0f1, acc0s1);
    ACT4(acc0s0, c0s0, h0f0[hwb + r * 8] = f2bf(hv));
    if (w >= 2 && w < 4 && t > 0) PROJ(h1f1, xf1);
    __syncthreads();

    // ===== R3: stores x0(t) ; cell1(s0) -> h1n0 ; x-part+act0(s1) -> h0f1 =====
    if (w < 2 && t > 0) {
      const long ob = obase0 + (long)t * 32;
      #pragma unroll
      for (int r = 0; r < 4; ++r) out[ob + r * rowStride] = xr[r];
    }
    float h1n0[4];
    {
      float4_t am[4];
      INIT4(am, b1r);
      CELL1A(h0f0, am);
      XPART(xf1, acc0s1);
      ACT4(acc0s1, c0s1, h0f1[hwb + r * 8] = f2bf(hv));
      CELL1B(h1f0, am);
      ACT4(am, c1s0, h1n0[r] = hv);
    }
    __syncthreads();

    // ===== R4: stores x1(t) ; h1f0 <- h1n0 ; cell1(s1) -> h1n1 =====
    if (w >= 2 && w < 4 && t > 0) {
      const long ob = obase0 + (long)t * 32;
      #pragma unroll
      for (int r = 0; r < 4; ++r) out[ob + r * rowStride] = xr[r];
    }
    #pragma unroll
    for (int r = 0; r < 4; ++r) h1f0[hwb + r * 8] = f2bf(h1n0[r]);
    {
      float4_t am[4];
      INIT4(am, b1r);
      CELL1A(h0f1, am);
      CELL1B(h1f1, am);
      ACT4(am, c1s1, h1n1[r] = hv);
    }
    __syncthreads();
  }

  // ===== Epilogue: final projections x(T) =====
  #pragma unroll
  for (int r = 0; r < 4; ++r) h1f1[hwb + r * 8] = f2bf(h1n1[r]);  // h1(T-1), s1
  if (w < 2) {   // x0(T): h1f0(T-1) published at last R4 barrier
    float4_t dacc = (float4_t){boutr, boutr, boutr, boutr};
    #pragma unroll
    for (int kt = 0; kt < 4; ++kt) {
      const bf16x8 a  = *(const bf16x8*)&h1f0[kt * 512 + l * 8];
      const bf16x8 bw = *(const bf16x8*)&woutF[(n_c * 4 + kt) * 512 + l * 8];
      dacc = MFMA(a, bw, dacc);
    }
    const long ob = obase0 + (long)T * 32;
    #pragma unroll
    for (int r = 0; r < 4; ++r) {
      xr[r] += dacc[r];
      out[ob + r * rowStride] = xr[r];
    }
  }
  __syncthreads();
  if (w >= 2 && w < 4) {   // x1(T)
    float4_t dacc = (float4_t){boutr, boutr, boutr, boutr};
    #pragma unroll
    for (int kt = 0; kt < 4; ++kt) {
      const bf16x8 a  = *(const bf16x8*)&h1f1[kt * 512 + l * 8];
      const bf16x8 bw = *(const bf16x8*)&woutF[(n_c * 4 + kt) * 512 + l * 8];
      dacc = MFMA(a, bw, dacc);
    }
    const long ob = obase0 + (long)T * 32;
    #pragma unroll
    for (int r = 0; r < 4; ++r) {
      xr[r] += dacc[r];
      out[ob + r * rowStride] = xr[r];
    }
  }
}

extern "C" void kernel_launch(void* const* d_in, const int* in_sizes, int n_in,
                              void* d_out, int out_size, void* d_ws, size_t ws_size,
                              hipStream_t stream) {
  (void)n_in; (void)out_size; (void)d_ws; (void)ws_size;
  const float* x0   = (const float*)d_in[0];
  const float* W0   = (const float*)d_in[1];
  const float* b0   = (const float*)d_in[2];
  const float* W1   = (const float*)d_in[3];
  const float* b1   = (const float*)d_in[4];
  const float* Wout = (const float*)d_in[5];
  const float* bout = (const float*)d_in[6];
  const float* dts  = (const float*)d_in[7];
  const int*   nsp  = (const int*)d_in[8];
  float* out = (float*)d_out;

  const int B    = in_sizes[0] / 32;   // 8192
  const int grid = B / 32;             // 256 blocks, 32 batch rows each
  lstm_roll<<<dim3(grid), dim3(512), 0, stream>>>(x0, W0, b0, W1, b1, Wout, bout, dts, nsp, out);
}

// Round 9
// 2280.258 us; speedup vs baseline: 1.3032x; 1.0135x over previous
//
#include <hip/hip_runtime.h>
#include <hip/hip_bf16.h>

typedef __bf16  bf16x8  __attribute__((ext_vector_type(8)));
typedef short   short8_t __attribute__((ext_vector_type(8)));
typedef float   float4_t __attribute__((ext_vector_type(4)));

#define MFMA(a, b, c) __builtin_amdgcn_mfma_f32_16x16x32_bf16((a), (b), (c), 0, 0, 0)

#define LOG2E      1.4426950408889634f
#define TWO_LOG2E  2.8853900817779268f

__device__ __forceinline__ unsigned short f2bf(float f) {
  unsigned u = __builtin_bit_cast(unsigned, f);
  unsigned r = ((u >> 16) & 1u) + 0x7FFFu;   // round-to-nearest-even
  return (unsigned short)((u + r) >> 16);
}
// x pre-scaled by LOG2E
__device__ __forceinline__ float sig2(float x) {
  return __builtin_amdgcn_rcpf(1.f + __builtin_amdgcn_exp2f(-x));
}
// x pre-scaled by 2*LOG2E
__device__ __forceinline__ float tanh2s(float x) {
  return 1.f - 2.f * __builtin_amdgcn_rcpf(1.f + __builtin_amdgcn_exp2f(x));
}

// 256 blocks x 512 threads (8 waves), 32 rows/block, TWO 16-row streams
// phase-shifted one region apart. Trans work equalized at ~40 ops/region by
// deferring each stream's act1 one region past its cell1 MFMAs (gates ride
// in MFMA C-registers across the barrier). Per step, 4 __syncthreads:
//   R1: cell0h(s0,t) 16 MFMA ; act1(s1,t-1) from am1 -> h1f1 ; proj(s0) [w<2]
//   R2: x-part+act0(s0) -> h0f0(t) ; cell0h(s1,t) ; proj(s1) [w=2,3]
//   R3: stores x0(t) ; cell1(s0) -> am0 (no act) ; x-part+act0(s1) -> h0f1(t)
//   R4: stores x1(t) ; act1(s0) from am0 -> h1f0 ; cell1(s1) -> am1 (no act)
__global__ __launch_bounds__(512, 2) void lstm_roll(
    const float* __restrict__ x0,  const float* __restrict__ W0,
    const float* __restrict__ b0v, const float* __restrict__ W1,
    const float* __restrict__ b1v, const float* __restrict__ Wout,
    const float* __restrict__ bout, const float* __restrict__ dts,
    const int* __restrict__ nsp,   float* __restrict__ out)
{
  __shared__ __align__(16) unsigned short w0h[8 * 4 * 4 * 512];  // 128 KiB W0 h-part B-frags [w][g][kt]
  __shared__ __align__(16) unsigned short woutF[2 * 4 * 512];    //   8 KiB Wout B-frags (dts*DT folded)
  __shared__ __align__(16) unsigned short h0f0[4 * 512];         //   4 KiB h0 A-frags, stream0
  __shared__ __align__(16) unsigned short h0f1[4 * 512];         //   4 KiB h0 A-frags, stream1
  __shared__ __align__(16) unsigned short h1f0[4 * 512];         //   4 KiB h1 A-frags, stream0
  __shared__ __align__(16) unsigned short h1f1[4 * 512];         //   4 KiB h1 A-frags, stream1
  __shared__ __align__(16) unsigned short xf0[512];              //   1 KiB x A-frag, stream0
  __shared__ __align__(16) unsigned short xf1[512];              //   1 KiB x A-frag, stream1

  const int tid = threadIdx.x;
  const int w   = tid >> 6;
  const int l   = tid & 63;
  const int lm  = l & 15;
  const int lh  = l >> 4;
  const int T   = nsp[0];
  const long rowStride = (long)(T + 1) * 32;
  const long bbase = (long)blockIdx.x * 32;

  // ---------------- weight gather / packing (once) ----------------
  bf16x8 w0x[4];       // W0 x-part B-frags (K=32)
  bf16x8 w1f[4][8];    // W1 B-frags (K=256; kt 0..3 h0-part, 4..7 h1-part)
  #pragma unroll
  for (int g = 0; g < 4; ++g) {
    const float sc = (g == 2) ? TWO_LOG2E : LOG2E;
    const int col = g * 128 + w * 16 + lm;
    {
      short8_t t8;
      #pragma unroll
      for (int e = 0; e < 8; ++e) t8[e] = (short)f2bf(sc * W0[(lh * 8 + e) * 512 + col]);
      w0x[g] = __builtin_bit_cast(bf16x8, t8);
    }
    #pragma unroll
    for (int kt = 0; kt < 8; ++kt) {
      short8_t t8;
      #pragma unroll
      for (int e = 0; e < 8; ++e) t8[e] = (short)f2bf(sc * W1[(kt * 32 + lh * 8 + e) * 512 + col]);
      w1f[g][kt] = __builtin_bit_cast(bf16x8, t8);
    }
    #pragma unroll
    for (int kt = 0; kt < 4; ++kt) {
      const int base = (((w * 4 + g) * 4) + kt) * 512 + l * 8;
      #pragma unroll
      for (int e = 0; e < 8; ++e)
        w0h[base + e] = f2bf(sc * W0[(32 + kt * 32 + lh * 8 + e) * 512 + col]);
    }
  }
  { // Wout B-frags with dts*DT folded in
    const int n = w & 1, kt = w >> 1;
    if (kt < 4) {
      const float csc = dts[n * 16 + lm] * 0.01f;
      const int base = (n * 4 + kt) * 512 + l * 8;
      #pragma unroll
      for (int e = 0; e < 8; ++e)
        woutF[base + e] = f2bf(csc * Wout[(kt * 32 + lh * 8 + e) * 32 + (n * 16 + lm)]);
    }
  }
  float b0r[4], b1r[4];
  #pragma unroll
  for (int g = 0; g < 4; ++g) {
    const float sc = (g == 2) ? TWO_LOG2E : LOG2E;
    b0r[g] = sc * b0v[g * 128 + w * 16 + lm];
    b1r[g] = sc * b1v[g * 128 + w * 16 + lm];
  }

  // proj/store mapping: waves 0,1 -> stream0 (n_c = w&1); waves 2,3 -> stream1
  const int S_w = (w >> 1) & 1;
  const int n_c = w & 1;
  float boutr = 0.f, xr[4] = {0.f, 0.f, 0.f, 0.f};
  long obase0 = 0;
  int  xfb = 0;
  if (w < 4) {
    boutr = bout[n_c * 16 + lm] * dts[n_c * 16 + lm] * 0.01f;
    const int kin = n_c * 16 + lm;
    xfb = (lh * 4 + 16 * (kin >> 3)) * 8 + (kin & 7);
    obase0 = (bbase + S_w * 16 + lh * 4) * rowStride + (n_c * 16 + lm);
    unsigned short* xfS = S_w ? xf1 : xf0;
    #pragma unroll
    for (int r = 0; r < 4; ++r) {
      xr[r] = x0[(bbase + S_w * 16 + lh * 4 + r) * 32 + n_c * 16 + lm];
      out[obase0 + r * rowStride] = xr[r];   // trajectory t = 0
      xfS[xfb + r * 8] = f2bf(xr[r]);        // seed xf(0)
    }
  }
  for (int i = tid; i < 4 * 512; i += 512) {
    h0f0[i] = 0; h0f1[i] = 0; h1f0[i] = 0; h1f1[i] = 0;
  }

  // h-write scatter base (per-stream fragment layout; kt = w>>1)
  const int hwb = (w >> 1) * 512 +
                  (lh * 4 + 16 * (2 * (w & 1) + ((lm >> 3) & 1))) * 8 + (lm & 7);

  float4_t c0s0 = {0.f,0.f,0.f,0.f}, c0s1 = {0.f,0.f,0.f,0.f};
  float4_t c1s0 = {0.f,0.f,0.f,0.f}, c1s1 = {0.f,0.f,0.f,0.f};

#define INIT4(ACC, B) \
    _Pragma("unroll") \
    for (int g = 0; g < 4; ++g) (ACC)[g] = (float4_t){(B)[g], (B)[g], (B)[g], (B)[g]};

#define CELL0H(HSRC, ACC) \
    _Pragma("unroll") \
    for (int kt = 0; kt < 4; ++kt) { \
      const bf16x8 a = *(const bf16x8*)&(HSRC)[kt * 512 + l * 8]; \
      _Pragma("unroll") \
      for (int g = 0; g < 4; ++g) { \
        const bf16x8 bw = *(const bf16x8*)&w0h[(((w * 4 + g) * 4) + kt) * 512 + l * 8]; \
        (ACC)[g] = MFMA(a, bw, (ACC)[g]); \
      } \
    }

#define XPART(XSRC, ACC) { \
    const bf16x8 ax = *(const bf16x8*)&(XSRC)[l * 8]; \
    _Pragma("unroll") \
    for (int g = 0; g < 4; ++g) (ACC)[g] = MFMA(ax, w0x[g], (ACC)[g]); \
  }

#define CELL1A(H0SRC, AM) \
    _Pragma("unroll") \
    for (int kt = 0; kt < 4; ++kt) { \
      const bf16x8 a = *(const bf16x8*)&(H0SRC)[kt * 512 + l * 8]; \
      _Pragma("unroll") \
      for (int g = 0; g < 4; ++g) (AM)[g] = MFMA(a, w1f[g][kt], (AM)[g]); \
    }
#define CELL1B(H1SRC, AM) \
    _Pragma("unroll") \
    for (int kt = 0; kt < 4; ++kt) { \
      const bf16x8 a = *(const bf16x8*)&(H1SRC)[kt * 512 + l * 8]; \
      _Pragma("unroll") \
      for (int g = 0; g < 4; ++g) (AM)[g] = MFMA(a, w1f[g][kt + 4], (AM)[g]); \
    }

#define ACT4(ACC, CS, DST) \
    _Pragma("unroll") \
    for (int r = 0; r < 4; ++r) { \
      const float iv = sig2((ACC)[0][r]); \
      const float fv = sig2((ACC)[1][r]); \
      const float gv = tanh2s((ACC)[2][r]); \
      const float ov = sig2((ACC)[3][r]); \
      const float cc = fv * (CS)[r] + iv * gv; \
      (CS)[r] = cc; \
      const float hv = ov * tanh2s(cc * TWO_LOG2E); \
      DST; \
    }

#define PROJ(H1SRC, XFDST) { \
    float4_t dacc = (float4_t){boutr, boutr, boutr, boutr}; \
    _Pragma("unroll") \
    for (int kt = 0; kt < 4; ++kt) { \
      const bf16x8 a  = *(const bf16x8*)&(H1SRC)[kt * 512 + l * 8]; \
      const bf16x8 bw = *(const bf16x8*)&woutF[(n_c * 4 + kt) * 512 + l * 8]; \
      dacc = MFMA(a, bw, dacc); \
    } \
    _Pragma("unroll") \
    for (int r = 0; r < 4; ++r) { \
      xr[r] += dacc[r]; \
      (XFDST)[xfb + r * 8] = f2bf(xr[r]); \
    } \
  }

  float4_t am1[4];            // s1's cell1 gates, pending act (crosses iters)
  INIT4(am1, b1r);

  __syncthreads();   // publish packing, xf seeds, h zeros

  #pragma unroll 1
  for (int t = 0; t < T; ++t) {
    // ===== R1: cell0h(s0) ; act1(s1,t-1) -> h1f1 ; proj(s0) =====
    float4_t acc0s0[4];
    INIT4(acc0s0, b0r);
    CELL0H(h0f0, acc0s0);
    if (t > 0) {
      ACT4(am1, c1s1, h1f1[hwb + r * 8] = f2bf(hv));
      if (w < 2) PROJ(h1f0, xf0);
    }
    __syncthreads();

    // ===== R2: x-part+act0(s0) -> h0f0 ; cell0h(s1) ; proj(s1) =====
    float4_t acc0s1[4];
    XPART(xf0, acc0s0);
    INIT4(acc0s1, b0r);
    CELL0H(h0f1, acc0s1);
    ACT4(acc0s0, c0s0, h0f0[hwb + r * 8] = f2bf(hv));
    if (w >= 2 && w < 4 && t > 0) PROJ(h1f1, xf1);
    __syncthreads();

    // ===== R3: stores x0(t) ; cell1(s0) -> am0 ; x-part+act0(s1) -> h0f1 =====
    if (w < 2 && t > 0) {
      const long ob = obase0 + (long)t * 32;
      #pragma unroll
      for (int r = 0; r < 4; ++r) out[ob + r * rowStride] = xr[r];
    }
    float4_t am0[4];
    INIT4(am0, b1r);
    CELL1A(h0f0, am0);
    XPART(xf1, acc0s1);
    ACT4(acc0s1, c0s1, h0f1[hwb + r * 8] = f2bf(hv));
    CELL1B(h1f0, am0);
    __syncthreads();

    // ===== R4: stores x1(t) ; act1(s0) -> h1f0 ; cell1(s1) -> am1 =====
    if (w >= 2 && w < 4 && t > 0) {
      const long ob = obase0 + (long)t * 32;
      #pragma unroll
      for (int r = 0; r < 4; ++r) out[ob + r * rowStride] = xr[r];
    }
    ACT4(am0, c1s0, h1f0[hwb + r * 8] = f2bf(hv));
    INIT4(am1, b1r);
    CELL1A(h0f1, am1);
    CELL1B(h1f1, am1);
    __syncthreads();
  }

  // ===== Epilogue: act1(s1,T-1) -> h1f1, then final projections x(T) =====
  ACT4(am1, c1s1, h1f1[hwb + r * 8] = f2bf(hv));
  if (w < 2) {   // x0(T): h1f0 holds h1(T-1), published at last R4 barrier
    float4_t dacc = (float4_t){boutr, boutr, boutr, boutr};
    #pragma unroll
    for (int kt = 0; kt < 4; ++kt) {
      const bf16x8 a  = *(const bf16x8*)&h1f0[kt * 512 + l * 8];
      const bf16x8 bw = *(const bf16x8*)&woutF[(n_c * 4 + kt) * 512 + l * 8];
      dacc = MFMA(a, bw, dacc);
    }
    const long ob = obase0 + (long)T * 32;
    #pragma unroll
    for (int r = 0; r < 4; ++r) {
      xr[r] += dacc[r];
      out[ob + r * rowStride] = xr[r];
    }
  }
  __syncthreads();   // publish h1f1
  if (w >= 2 && w < 4) {   // x1(T)
    float4_t dacc = (float4_t){boutr, boutr, boutr, boutr};
    #pragma unroll
    for (int kt = 0; kt < 4; ++kt) {
      const bf16x8 a  = *(const bf16x8*)&h1f1[kt * 512 + l * 8];
      const bf16x8 bw = *(const bf16x8*)&woutF[(n_c * 4 + kt) * 512 + l * 8];
      dacc = MFMA(a, bw, dacc);
    }
    const long ob = obase0 + (long)T * 32;
    #pragma unroll
    for (int r = 0; r < 4; ++r) {
      xr[r] += dacc[r];
      out[ob + r * rowStride] = xr[r];
    }
  }
}

extern "C" void kernel_launch(void* const* d_in, const int* in_sizes, int n_in,
                              void* d_out, int out_size, void* d_ws, size_t ws_size,
                              hipStream_t stream) {
  (void)n_in; (void)out_size; (void)d_ws; (void)ws_size;
  const float* x0   = (const float*)d_in[0];
  const float* W0   = (const float*)d_in[1];
  const float* b0   = (const float*)d_in[2];
  const float* W1   = (const float*)d_in[3];
  const float* b1   = (const float*)d_in[4];
  const float* Wout = (const float*)d_in[5];
  const float* bout = (const float*)d_in[6];
  const float* dts  = (const float*)d_in[7];
  const int*   nsp  = (const int*)d_in[8];
  float* out = (float*)d_out;

  const int B    = in_sizes[0] / 32;   // 8192
  const int grid = B / 32;             // 256 blocks, 32 batch rows each
  lstm_roll<<<dim3(grid), dim3(512), 0, stream>>>(x0, W0, b0, W1, b1, Wout, bout, dts, nsp, out);
}